// Round 6
// baseline (631.708 us; speedup 1.0000x reference)
//
#include <hip/hip_runtime.h>
#include <stdint.h>

// ---- problem constants ----
#define NWINDOWS 2048          // B*N_WIN = 32*64

typedef short bf16x8 __attribute__((ext_vector_type(8)));
typedef float f32x4  __attribute__((ext_vector_type(4)));

// workspace layout (bytes)
#define OFF_WQKV  0u           // 768*256 bf16  = 393216
#define OFF_WPROJ 393216u      // 256*256 bf16  = 131072
#define OFF_BQKV  524288u      // 768 f32       = 3072
#define OFF_BIAS  527360u      // 32*64*64 f32  = 524288
#define WS_NEED   1051648u

__device__ __forceinline__ unsigned short f2bf(float f) {
    union { float f; unsigned int u; } v; v.f = f;
    unsigned int u = v.u;
    u += 0x7FFFu + ((u >> 16) & 1u);     // RNE
    return (unsigned short)(u >> 16);
}

// ---------------- K0: prep (weights->bf16, fold q-scale, bias table) --------
__global__ __launch_bounds__(256)
void prep_kernel(const float* __restrict__ qkv_w, const float* __restrict__ qkv_b,
                 const float* __restrict__ proj_w, const float* __restrict__ theta_max,
                 const float* __restrict__ a_p, const float* __restrict__ b_p,
                 const float* __restrict__ a_r, const float* __restrict__ b_r,
                 const int* __restrict__ radius, const int* __restrict__ azimuth,
                 unsigned short* __restrict__ w_qkv, unsigned short* __restrict__ w_proj,
                 float* __restrict__ b_qkv, float* __restrict__ bias_tbl)
{
    int idx = blockIdx.x * 256 + threadIdx.x;
    const float scale = 0.0625f;                    // head_dim^-0.5 = 1/16
    if (idx < 196608) {                             // qkv_w -> bf16 (q rows scaled)
        int row = idx >> 8;
        float v = qkv_w[idx];
        if (row < 256) v *= scale;
        w_qkv[idx] = f2bf(v);
    } else if (idx < 196608 + 65536) {              // proj_w -> bf16
        int j = idx - 196608;
        w_proj[j] = f2bf(proj_w[j]);
    } else if (idx < 196608 + 65536 + 768) {        // qkv_b (scaled), kept f32
        int j = idx - (196608 + 65536);
        float v = qkv_b[j];
        if (j < 256) v *= scale;
        b_qkv[j] = v;
    } else if (idx < 196608 + 65536 + 768 + 131072) {  // bias_tbl[32][64][64]
        int j = idx - (196608 + 65536 + 768);
        int b  = j >> 12;
        int ij = j & 4095;
        int az = azimuth[ij];
        int rd = radius[ij];
        int aidx = az < 0 ? az + 15 : az;
        int ridx = rd < 0 ? rd + 15 : rd;
        float azf = (float)az * 0.09817477042468103f;   // 2*pi/64
        float phi = a_p[aidx] * cosf(azf) + b_p[aidx] * sinf(azf);
        float rn  = (float)rd * theta_max[b] * 0.015625f; // /64
        bias_tbl[j] = phi + a_r[ridx] * cosf(rn) + b_r[ridx] * sinf(rn);
    }
}

// ---------------- K1: fully fused  x -> QKV -> attention -> proj -> out -----
// One block per 64-token window. x rows held as A-frags in registers (one
// wave owns 16 tokens); Q/K/V computed against L2-resident w_qkv and kept
// entirely in LDS (never touch HBM). Eliminates the 402 MB qkv round-trip.
// LDS overlays (74 KB -> 2 blocks/CU, 2 waves/SIMD, 256-VGPR budget):
//   R1 (33.8 KB): Q-pane (phase 1) -> K swizzled (2-3) -> Ol (4-5)
//   vT (32 KB):   V transposed+swizzled (2-4)
//   Pl (9 KB):    P (4)
__global__ __launch_bounds__(256, 2)
void fused_attn(const float* __restrict__ x, const unsigned short* __restrict__ w_qkv,
                const float* __restrict__ b_qkv, const float* __restrict__ bias_tbl,
                const unsigned short* __restrict__ w_proj, const float* __restrict__ proj_b,
                float* __restrict__ out)
{
    __shared__ __align__(16) unsigned short R1[4 * 16 * 264];  // 33792 B
    __shared__ __align__(16) unsigned short vT[256 * 64];      // 32768 B
    __shared__ __align__(16) unsigned short Pl[64 * 72];       //  9216 B

    const int win   = blockIdx.x;
    const int batch = win >> 6;
    const size_t rowbase = (size_t)win * 64;
    const int tid  = threadIdx.x;
    const int w    = tid >> 6;
    const int lane = tid & 63;
    const int quad = lane >> 4;
    const int l16  = lane & 15;
    const int m3   = l16 & 7;

    // ---- p0: x A-frags, wave's 16 token rows x K=256 (fp32->bf16, 32 VGPR)
    bf16x8 af[8];
    {
        const float* xrow = x + (rowbase + w * 16 + l16) * 256;
        #pragma unroll
        for (int kk = 0; kk < 8; ++kk) {
            const float4* p = (const float4*)(xrow + kk * 32 + quad * 8);
            float4 v0 = p[0], v1 = p[1];
            bf16x8 a;
            a[0] = (short)f2bf(v0.x); a[1] = (short)f2bf(v0.y);
            a[2] = (short)f2bf(v0.z); a[3] = (short)f2bf(v0.w);
            a[4] = (short)f2bf(v1.x); a[5] = (short)f2bf(v1.y);
            a[6] = (short)f2bf(v1.z); a[7] = (short)f2bf(v1.w);
            af[kk] = a;
        }
    }

    // ---- p1: Q = x @ Wq^T + bq (pre-scaled). C-layout -> wave-private pane
    // -> read back as A-frags (qf). Two independent acc chains per ct-pair.
    unsigned short* const qp = R1 + w * (16 * 264);
    #pragma unroll 2
    for (int cp = 0; cp < 8; ++cp) {
        const int c0 = cp * 2, c1 = cp * 2 + 1;
        const unsigned short* wp0 = w_qkv + (c0 * 16 + l16) * 256 + quad * 8;
        const unsigned short* wp1 = w_qkv + (c1 * 16 + l16) * 256 + quad * 8;
        bf16x8 b0[8], b1[8];
        #pragma unroll
        for (int kk = 0; kk < 8; ++kk) {
            b0[kk] = *(const bf16x8*)(wp0 + kk * 32);
            b1[kk] = *(const bf16x8*)(wp1 + kk * 32);
        }
        f32x4 a0 = {0.f,0.f,0.f,0.f}, a1 = {0.f,0.f,0.f,0.f};
        #pragma unroll
        for (int kk = 0; kk < 8; ++kk) {
            a0 = __builtin_amdgcn_mfma_f32_16x16x32_bf16(af[kk], b0[kk], a0, 0, 0, 0);
            a1 = __builtin_amdgcn_mfma_f32_16x16x32_bf16(af[kk], b1[kk], a1, 0, 0, 0);
        }
        const float bias0 = b_qkv[c0 * 16 + l16];
        const float bias1 = b_qkv[c1 * 16 + l16];
        #pragma unroll
        for (int r = 0; r < 4; ++r) {
            qp[(quad * 4 + r) * 264 + c0 * 16 + l16] = f2bf(a0[r] + bias0);
            qp[(quad * 4 + r) * 264 + c1 * 16 + l16] = f2bf(a1[r] + bias1);
        }
    }
    bf16x8 qf[8];
    #pragma unroll
    for (int kk = 0; kk < 8; ++kk)
        qf[kk] = *(const bf16x8*)(qp + l16 * 264 + kk * 32 + quad * 8);

    __syncthreads();   // Q-pane consumed; R1 free for K

    // ---- p2: K,V = x @ {Wk,Wv}^T + b. K -> R1 rows [tok][256] with 16B-chunk
    // XOR swizzle (phys = (c>>3)^(tok&7)); V -> vT[d][swz(tok,d)] scatter.
    for (int ct = 0; ct < 16; ++ct) {
        const unsigned short* wpk = w_qkv + (256 + ct * 16 + l16) * 256 + quad * 8;
        const unsigned short* wpv = w_qkv + (512 + ct * 16 + l16) * 256 + quad * 8;
        bf16x8 bk[8], bv[8];
        #pragma unroll
        for (int kk = 0; kk < 8; ++kk) {
            bk[kk] = *(const bf16x8*)(wpk + kk * 32);
            bv[kk] = *(const bf16x8*)(wpv + kk * 32);
        }
        f32x4 ak = {0.f,0.f,0.f,0.f}, av = {0.f,0.f,0.f,0.f};
        #pragma unroll
        for (int kk = 0; kk < 8; ++kk) {
            ak = __builtin_amdgcn_mfma_f32_16x16x32_bf16(af[kk], bk[kk], ak, 0, 0, 0);
            av = __builtin_amdgcn_mfma_f32_16x16x32_bf16(af[kk], bv[kk], av, 0, 0, 0);
        }
        const float biask = b_qkv[256 + ct * 16 + l16];
        const float biasv = b_qkv[512 + ct * 16 + l16];
        const int c = ct * 16 + l16;
        #pragma unroll
        for (int r = 0; r < 4; ++r) {
            int tk = w * 16 + quad * 4 + r;
            R1[tk * 256 + ((((c >> 3) ^ (tk & 7)) << 3) | (c & 7))] = f2bf(ak[r] + biask);
            int swz = (((tk >> 3) ^ (c & 7)) << 3) | (tk & 7);
            vT[c * 64 + swz] = f2bf(av[r] + biasv);
        }
    }

    __syncthreads();   // K, vT ready

    // ---- p3: S = Q K^T (+bias), register softmax, P -> Pl
    f32x4 S[4];
    #pragma unroll
    for (int t = 0; t < 4; ++t) {
        f32x4 c = {0.f, 0.f, 0.f, 0.f};
        const unsigned short* kr = R1 + (t * 16 + l16) * 256;
        #pragma unroll
        for (int kk = 0; kk < 8; ++kk) {
            bf16x8 b = *(const bf16x8*)(kr + ((((kk << 2) | quad) ^ m3) << 3));
            c = __builtin_amdgcn_mfma_f32_16x16x32_bf16(qf[kk], b, c, 0, 0, 0);
        }
        S[t] = c;
    }

    const float* bt = bias_tbl + batch * 4096 + (w * 16 + quad * 4) * 64 + l16;
    #pragma unroll
    for (int t = 0; t < 4; ++t)
        #pragma unroll
        for (int r = 0; r < 4; ++r)
            S[t][r] += bt[r * 64 + t * 16];

    float inv[4];
    #pragma unroll
    for (int r = 0; r < 4; ++r) {
        float m = fmaxf(fmaxf(S[0][r], S[1][r]), fmaxf(S[2][r], S[3][r]));
        #pragma unroll
        for (int off = 1; off < 16; off <<= 1)
            m = fmaxf(m, __shfl_xor(m, off, 64));
        float s = 0.f;
        #pragma unroll
        for (int t = 0; t < 4; ++t) { S[t][r] = __expf(S[t][r] - m); s += S[t][r]; }
        #pragma unroll
        for (int off = 1; off < 16; off <<= 1)
            s += __shfl_xor(s, off, 64);
        inv[r] = 1.0f / s;
    }

    #pragma unroll
    for (int t = 0; t < 4; ++t)
        #pragma unroll
        for (int r = 0; r < 4; ++r)
            Pl[(w * 16 + quad * 4 + r) * 72 + t * 16 + l16] = f2bf(S[t][r] * inv[r]);

    __syncthreads();   // all S K-reads done (R1 free for Ol); P ready

    // ---- p4: O = P V -> Ol (R1, pitch 264)
    #pragma unroll
    for (int n = 0; n < 16; ++n) {
        f32x4 c = {0.f, 0.f, 0.f, 0.f};
        int dim = n * 16 + l16;
        #pragma unroll
        for (int kk = 0; kk < 2; ++kk) {
            bf16x8 a = *(const bf16x8*)(&Pl[(w * 16 + l16) * 72 + kk * 32 + quad * 8]);
            int chunk = (kk * 4 + quad) ^ (dim & 7);
            bf16x8 b = *(const bf16x8*)(&vT[dim * 64 + chunk * 8]);
            c = __builtin_amdgcn_mfma_f32_16x16x32_bf16(a, b, c, 0, 0, 0);
        }
        #pragma unroll
        for (int r = 0; r < 4; ++r)
            R1[(w * 16 + quad * 4 + r) * 264 + dim] = f2bf(c[r]);
    }

    __syncthreads();   // Ol ready

    // ---- p5: proj: wave w computes all 64 rows x cols [w*64, w*64+64)
    bf16x8 pf[4][8];
    #pragma unroll
    for (int rt = 0; rt < 4; ++rt)
        #pragma unroll
        for (int kk = 0; kk < 8; ++kk)
            pf[rt][kk] = *(const bf16x8*)(&R1[(rt * 16 + l16) * 264 + kk * 32 + quad * 8]);

    #pragma unroll
    for (int ntl = 0; ntl < 4; ++ntl) {
        int ncol = w * 64 + ntl * 16 + l16;
        const unsigned short* wp = w_proj + ncol * 256 + quad * 8;
        f32x4 acc[4] = {{0,0,0,0},{0,0,0,0},{0,0,0,0},{0,0,0,0}};
        #pragma unroll
        for (int kk = 0; kk < 8; ++kk) {
            bf16x8 b = *(const bf16x8*)(wp + kk * 32);
            #pragma unroll
            for (int rt = 0; rt < 4; ++rt)
                acc[rt] = __builtin_amdgcn_mfma_f32_16x16x32_bf16(pf[rt][kk], b, acc[rt], 0, 0, 0);
        }
        float pb = proj_b[ncol];
        #pragma unroll
        for (int rt = 0; rt < 4; ++rt)
            #pragma unroll
            for (int r = 0; r < 4; ++r)
                out[(rowbase + rt * 16 + quad * 4 + r) * 256 + ncol] = acc[rt][r] + pb;
    }
}

// ---------------- launch ----------------------------------------------------
extern "C" void kernel_launch(void* const* d_in, const int* in_sizes, int n_in,
                              void* d_out, int out_size, void* d_ws, size_t ws_size,
                              hipStream_t stream)
{
    const float* x       = (const float*)d_in[0];
    const float* theta   = (const float*)d_in[1];
    const float* qkv_w   = (const float*)d_in[2];
    const float* qkv_b   = (const float*)d_in[3];
    const float* proj_w  = (const float*)d_in[4];
    const float* proj_b  = (const float*)d_in[5];
    const float* a_p     = (const float*)d_in[6];
    const float* b_p     = (const float*)d_in[7];
    const float* a_r     = (const float*)d_in[8];
    const float* b_r     = (const float*)d_in[9];
    const int*   radius  = (const int*)d_in[10];
    const int*   azimuth = (const int*)d_in[11];

    if (ws_size < (size_t)WS_NEED) return;

    char* ws = (char*)d_ws;
    unsigned short* w_qkv    = (unsigned short*)(ws + OFF_WQKV);
    unsigned short* w_proj   = (unsigned short*)(ws + OFF_WPROJ);
    float*          b_qkv    = (float*)(ws + OFF_BQKV);
    float*          bias_tbl = (float*)(ws + OFF_BIAS);

    prep_kernel<<<1540, 256, 0, stream>>>(qkv_w, qkv_b, proj_w, theta,
                                          a_p, b_p, a_r, b_r, radius, azimuth,
                                          w_qkv, w_proj, b_qkv, bias_tbl);
    fused_attn<<<NWINDOWS, 256, 0, stream>>>(x, w_qkv, b_qkv, bias_tbl,
                                             w_proj, proj_b, (float*)d_out);
}

// Round 8
// 407.230 us; speedup vs baseline: 1.5512x; 1.5512x over previous
//
#include <hip/hip_runtime.h>
#include <stdint.h>

// ---- problem constants ----
#define NWINDOWS 2048          // B*N_WIN = 32*64

typedef short bf16x8 __attribute__((ext_vector_type(8)));
typedef float f32x4  __attribute__((ext_vector_type(4)));

// workspace layout (bytes)
#define OFF_WQKV  0u           // 768*256 bf16  = 393216
#define OFF_WPROJ 393216u      // 256*256 bf16  = 131072
#define OFF_BQKV  524288u      // 768 f32       = 3072
#define OFF_BIAS  527360u      // 32*64*64 f32  = 524288
#define WS_NEED   1051648u

__device__ __forceinline__ unsigned short f2bf(float f) {
    union { float f; unsigned int u; } v; v.f = f;
    unsigned int u = v.u;
    u += 0x7FFFu + ((u >> 16) & 1u);     // RNE
    return (unsigned short)(u >> 16);
}

// ---------------- K0: prep (weights->bf16, fold q-scale, bias table) --------
__global__ __launch_bounds__(256)
void prep_kernel(const float* __restrict__ qkv_w, const float* __restrict__ qkv_b,
                 const float* __restrict__ proj_w, const float* __restrict__ theta_max,
                 const float* __restrict__ a_p, const float* __restrict__ b_p,
                 const float* __restrict__ a_r, const float* __restrict__ b_r,
                 const int* __restrict__ radius, const int* __restrict__ azimuth,
                 unsigned short* __restrict__ w_qkv, unsigned short* __restrict__ w_proj,
                 float* __restrict__ b_qkv, float* __restrict__ bias_tbl)
{
    int idx = blockIdx.x * 256 + threadIdx.x;
    const float scale = 0.0625f;                    // head_dim^-0.5 = 1/16
    if (idx < 196608) {                             // qkv_w -> bf16 (q rows scaled)
        int row = idx >> 8;
        float v = qkv_w[idx];
        if (row < 256) v *= scale;
        w_qkv[idx] = f2bf(v);
    } else if (idx < 196608 + 65536) {              // proj_w -> bf16
        int j = idx - 196608;
        w_proj[j] = f2bf(proj_w[j]);
    } else if (idx < 196608 + 65536 + 768) {        // qkv_b (scaled), kept f32
        int j = idx - (196608 + 65536);
        float v = qkv_b[j];
        if (j < 256) v *= scale;
        b_qkv[j] = v;
    } else if (idx < 196608 + 65536 + 768 + 131072) {  // bias_tbl[32][64][64]
        int j = idx - (196608 + 65536 + 768);
        int b  = j >> 12;
        int ij = j & 4095;
        int az = azimuth[ij];
        int rd = radius[ij];
        int aidx = az < 0 ? az + 15 : az;
        int ridx = rd < 0 ? rd + 15 : rd;
        float azf = (float)az * 0.09817477042468103f;   // 2*pi/64
        float phi = a_p[aidx] * cosf(azf) + b_p[aidx] * sinf(azf);
        float rn  = (float)rd * theta_max[b] * 0.015625f; // /64
        bias_tbl[j] = phi + a_r[ridx] * cosf(rn) + b_r[ridx] * sinf(rn);
    }
}

// ---------------- K1: fully fused  x -> QKV -> attention -> proj -> out -----
// v7: v6's fused structure + v3's PROVEN LDS weight staging. Unified 48-tile
// staged GEMM (Q tiles 0-15 -> per-wave panes; K 16-31 -> sK; V 32-47 -> sQV
// scatter), double-buffered 8 KB ring via global_load_lds (1 KB-contiguous,
// shared by all 4 waves -- kills v6's 4x per-wave redundant scattered loads).
// LDS overlays, exactly 80 KB -> 2 blocks/CU:
//   sK  (32 KB): K swizzled -> Ol (after p3 barrier)
//   sQV (32 KB): Q-panes (qf readback before tile 16) -> V^T
//   sPB ( 8 KB): ring slot1 (dead after tile 47) -> P panes
//   sRA ( 8 KB): ring slot0
// All LDS tensors use one involution: phys_chunk = logical_chunk ^ (row&7).
__global__ __launch_bounds__(256, 2)
void fused_attn(const float* __restrict__ x, const unsigned short* __restrict__ w_qkv,
                const float* __restrict__ b_qkv, const float* __restrict__ bias_tbl,
                const unsigned short* __restrict__ w_proj, const float* __restrict__ proj_b,
                float* __restrict__ out)
{
    __shared__ __align__(16) unsigned short sK[64 * 256];   // 32768 B
    __shared__ __align__(16) unsigned short sQV[64 * 256];  // 32768 B
    __shared__ __align__(16) unsigned short sPB[4096];      //  8192 B
    __shared__ __align__(16) unsigned short sRA[4096];      //  8192 B

    const int win   = blockIdx.x;
    const int batch = win >> 6;
    const size_t rowbase = (size_t)win * 64;
    const int tid  = threadIdx.x;
    const int w    = tid >> 6;
    const int lane = tid & 63;
    const int quad = lane >> 4;
    const int l16  = lane & 15;
    const int m3   = l16 & 7;

    // ---- staging (byte-for-byte v3): thread covers row tid>>5 (+8 on 2nd
    // instr), phys 16B slot tid&31 holds logical chunk slot^(row&7).
    const int srow = tid >> 5;
    const int sc   = (tid & 31) ^ (srow & 7);

    auto stage = [&](int nt, unsigned short* slot) {
        const unsigned short* s0 = w_qkv + (nt * 16 + srow) * 256 + sc * 8;
        unsigned short* d = slot + w * 512;
        __builtin_amdgcn_global_load_lds(
            (const __attribute__((address_space(1))) void*)s0,
            (__attribute__((address_space(3))) void*)d, 16, 0, 0);
        __builtin_amdgcn_global_load_lds(
            (const __attribute__((address_space(1))) void*)(s0 + 8 * 256),
            (__attribute__((address_space(3))) void*)(d + 2048), 16, 0, 0);
    };

    stage(0, sRA);                       // overlap with x loads below

    // ---- p0: x A-frags, wave's 16 token rows x K=256 (fp32->bf16, 32 VGPR)
    bf16x8 af[8];
    {
        const float* xrow = x + (rowbase + w * 16 + l16) * 256;
        #pragma unroll
        for (int kk = 0; kk < 8; ++kk) {
            const float4* p = (const float4*)(xrow + kk * 32 + quad * 8);
            float4 v0 = p[0], v1 = p[1];
            bf16x8 a;
            a[0] = (short)f2bf(v0.x); a[1] = (short)f2bf(v0.y);
            a[2] = (short)f2bf(v0.z); a[3] = (short)f2bf(v0.w);
            a[4] = (short)f2bf(v1.x); a[5] = (short)f2bf(v1.y);
            a[6] = (short)f2bf(v1.z); a[7] = (short)f2bf(v1.w);
            af[kk] = a;
        }
    }

    __syncthreads();                     // stage(0) landed

    // ---- unified staged QKV loop: 48 tiles of 16 output cols ----
    bf16x8 qf[8];
    for (int nt = 0; nt < 48; ++nt) {
        unsigned short* cur = (nt & 1) ? sPB : sRA;
        unsigned short* nxt = (nt & 1) ? sRA : sPB;
        if (nt + 1 < 48) stage(nt + 1, nxt);

        // two independent 4-MFMA chains (B-read = v3-verbatim swizzle)
        f32x4 accA = {0.f,0.f,0.f,0.f}, accB = {0.f,0.f,0.f,0.f};
        const unsigned short* bsr = cur + l16 * 256;
        #pragma unroll
        for (int kk = 0; kk < 4; ++kk) {
            bf16x8 b0 = *(const bf16x8*)(bsr + ((((kk << 2) | quad) ^ m3) << 3));
            bf16x8 b1 = *(const bf16x8*)(bsr + (((((kk + 4) << 2) | quad) ^ m3) << 3));
            accA = __builtin_amdgcn_mfma_f32_16x16x32_bf16(af[kk],     b0, accA, 0, 0, 0);
            accB = __builtin_amdgcn_mfma_f32_16x16x32_bf16(af[kk + 4], b1, accB, 0, 0, 0);
        }
        const float bias = b_qkv[nt * 16 + l16];

        if (nt < 16) {                   // Q -> wave-private pane in sQV
            #pragma unroll
            for (int r = 0; r < 4; ++r) {
                int row = quad * 4 + r;
                int cc  = (nt * 2 + (l16 >> 3)) ^ (row & 7);
                sQV[w * 4096 + row * 256 + cc * 8 + (l16 & 7)] =
                    f2bf(accA[r] + accB[r] + bias);
            }
        } else if (nt < 32) {            // K -> sK rows [tok][256] swizzled
            int c = (nt - 16) * 16 + l16;
            #pragma unroll
            for (int r = 0; r < 4; ++r) {
                int tk = w * 16 + quad * 4 + r;
                sK[tk * 256 + ((((c >> 3) ^ (tk & 7)) << 3) | (c & 7))] =
                    f2bf(accA[r] + accB[r] + bias);
            }
        } else {                         // V -> sQV as V^T[dim][tok] scatter
            int d = (nt - 32) * 16 + l16;
            #pragma unroll
            for (int r = 0; r < 4; ++r) {
                int tk  = w * 16 + quad * 4 + r;
                int swz = (((tk >> 3) ^ (d & 7)) << 3) | (tk & 7);
                sQV[d * 64 + swz] = f2bf(accA[r] + accB[r] + bias);
            }
        }

        if (nt == 15) {                  // qf readback (wave-private pane;
            #pragma unroll               //  barriers keep V-writes >=16 tiles away)
            for (int kk = 0; kk < 8; ++kk) {
                int ph = ((kk << 2) | quad) ^ m3;
                qf[kk] = *(const bf16x8*)(&sQV[w * 4096 + l16 * 256 + ph * 8]);
            }
        }
        __syncthreads();                 // stage(nt+1) landed; cur readers done
    }

    // ---- p3: S = Q K^T (+bias), register softmax, P -> per-wave sPB panes
    f32x4 S[4];
    #pragma unroll
    for (int t = 0; t < 4; ++t) {
        f32x4 c = {0.f, 0.f, 0.f, 0.f};
        const unsigned short* kr = sK + (t * 16 + l16) * 256;
        #pragma unroll
        for (int kk = 0; kk < 8; ++kk) {
            bf16x8 b = *(const bf16x8*)(kr + ((((kk << 2) | quad) ^ m3) << 3));
            c = __builtin_amdgcn_mfma_f32_16x16x32_bf16(qf[kk], b, c, 0, 0, 0);
        }
        S[t] = c;
    }

    const float* bt = bias_tbl + batch * 4096 + (w * 16 + quad * 4) * 64 + l16;
    #pragma unroll
    for (int t = 0; t < 4; ++t)
        #pragma unroll
        for (int r = 0; r < 4; ++r)
            S[t][r] += bt[r * 64 + t * 16];

    float inv[4];
    #pragma unroll
    for (int r = 0; r < 4; ++r) {
        float m = fmaxf(fmaxf(S[0][r], S[1][r]), fmaxf(S[2][r], S[3][r]));
        #pragma unroll
        for (int off = 1; off < 16; off <<= 1)
            m = fmaxf(m, __shfl_xor(m, off, 64));
        float s = 0.f;
        #pragma unroll
        for (int t = 0; t < 4; ++t) { S[t][r] = __expf(S[t][r] - m); s += S[t][r]; }
        #pragma unroll
        for (int off = 1; off < 16; off <<= 1)
            s += __shfl_xor(s, off, 64);
        inv[r] = 1.0f / s;
    }

    #pragma unroll
    for (int t = 0; t < 4; ++t)
        #pragma unroll
        for (int r = 0; r < 4; ++r) {
            int row = quad * 4 + r;                      // pane-local row
            int cc  = (t * 2 + (l16 >> 3)) ^ (row & 7);  // 8-chunk involution
            sPB[w * 1024 + row * 64 + cc * 8 + (l16 & 7)] = f2bf(S[t][r] * inv[r]);
        }

    __syncthreads();   // all K-reads done (sK free for Ol); P, vT ready

    // ---- p4: O = P V -> Ol (sK, pitch 256 swizzled)
    #pragma unroll
    for (int n = 0; n < 16; ++n) {
        f32x4 c = {0.f, 0.f, 0.f, 0.f};
        int dim = n * 16 + l16;
        #pragma unroll
        for (int kk = 0; kk < 2; ++kk) {
            bf16x8 a = *(const bf16x8*)(&sPB[w * 1024 + l16 * 64 +
                                             (((kk * 4 + quad) ^ m3) << 3)]);
            int chunk = (kk * 4 + quad) ^ (dim & 7);
            bf16x8 b = *(const bf16x8*)(&sQV[dim * 64 + chunk * 8]);
            c = __builtin_amdgcn_mfma_f32_16x16x32_bf16(a, b, c, 0, 0, 0);
        }
        #pragma unroll
        for (int r = 0; r < 4; ++r) {
            int row = w * 16 + quad * 4 + r;
            int cc  = (2 * n + (l16 >> 3)) ^ (row & 7);
            sK[row * 256 + cc * 8 + (l16 & 7)] = f2bf(c[r]);
        }
    }

    __syncthreads();   // Ol ready

    // ---- p5: proj: wave w computes all 64 rows x cols [w*64, w*64+64)
    bf16x8 pf[4][8];
    #pragma unroll
    for (int rt = 0; rt < 4; ++rt)
        #pragma unroll
        for (int kk = 0; kk < 8; ++kk)
            pf[rt][kk] = *(const bf16x8*)(&sK[(rt * 16 + l16) * 256 +
                                              ((((kk << 2) | quad) ^ m3) << 3)]);

    #pragma unroll
    for (int ntl = 0; ntl < 4; ++ntl) {
        int ncol = w * 64 + ntl * 16 + l16;
        const unsigned short* wp = w_proj + ncol * 256 + quad * 8;
        f32x4 acc[4] = {{0,0,0,0},{0,0,0,0},{0,0,0,0},{0,0,0,0}};
        #pragma unroll
        for (int kk = 0; kk < 8; ++kk) {
            bf16x8 b = *(const bf16x8*)(wp + kk * 32);
            #pragma unroll
            for (int rt = 0; rt < 4; ++rt)
                acc[rt] = __builtin_amdgcn_mfma_f32_16x16x32_bf16(pf[rt][kk], b, acc[rt], 0, 0, 0);
        }
        float pb = proj_b[ncol];
        #pragma unroll
        for (int rt = 0; rt < 4; ++rt)
            #pragma unroll
            for (int r = 0; r < 4; ++r)
                out[(rowbase + rt * 16 + quad * 4 + r) * 256 + ncol] = acc[rt][r] + pb;
    }
}

// ---------------- launch ----------------------------------------------------
extern "C" void kernel_launch(void* const* d_in, const int* in_sizes, int n_in,
                              void* d_out, int out_size, void* d_ws, size_t ws_size,
                              hipStream_t stream)
{
    const float* x       = (const float*)d_in[0];
    const float* theta   = (const float*)d_in[1];
    const float* qkv_w   = (const float*)d_in[2];
    const float* qkv_b   = (const float*)d_in[3];
    const float* proj_w  = (const float*)d_in[4];
    const float* proj_b  = (const float*)d_in[5];
    const float* a_p     = (const float*)d_in[6];
    const float* b_p     = (const float*)d_in[7];
    const float* a_r     = (const float*)d_in[8];
    const float* b_r     = (const float*)d_in[9];
    const int*   radius  = (const int*)d_in[10];
    const int*   azimuth = (const int*)d_in[11];

    if (ws_size < (size_t)WS_NEED) return;

    char* ws = (char*)d_ws;
    unsigned short* w_qkv    = (unsigned short*)(ws + OFF_WQKV);
    unsigned short* w_proj   = (unsigned short*)(ws + OFF_WPROJ);
    float*          b_qkv    = (float*)(ws + OFF_BQKV);
    float*          bias_tbl = (float*)(ws + OFF_BIAS);

    prep_kernel<<<1540, 256, 0, stream>>>(qkv_w, qkv_b, proj_w, theta,
                                          a_p, b_p, a_r, b_r, radius, azimuth,
                                          w_qkv, w_proj, b_qkv, bias_tbl);
    fused_attn<<<NWINDOWS, 256, 0, stream>>>(x, w_qkv, b_qkv, bias_tbl,
                                             w_proj, proj_b, (float*)d_out);
}